// Round 1
// baseline (1057.150 us; speedup 1.0000x reference)
//
#include <hip/hip_runtime.h>

typedef unsigned short u16;
typedef __bf16 bf16x8 __attribute__((ext_vector_type(8)));
typedef float f32x4 __attribute__((ext_vector_type(4)));

#define T_STEPS 64
#define BATCH 32
#define HDIM 1024
#define EDIM 512
#define VDIM 32000
#define GDIM 4096  // 4*H

// fp32 -> bf16 round-to-nearest-even (matches XLA convert)
__device__ __forceinline__ u16 f2b(float v) {
  unsigned x = __float_as_uint(v);
  return (u16)((x + 0x7fffu + ((x >> 16) & 1u)) >> 16);
}

// async global->LDS, 16B per lane; lds dest = wave-uniform base + lane*16
__device__ __forceinline__ void gload16(const void* g, void* l) {
  __builtin_amdgcn_global_load_lds(
      (const __attribute__((address_space(1))) void*)g,
      (__attribute__((address_space(3))) void*)l, 16, 0, 0);
}

__device__ __forceinline__ f32x4 mfma16(bf16x8 a, bf16x8 b, f32x4 c) {
  return __builtin_amdgcn_mfma_f32_16x16x32_bf16(a, b, c, 0, 0, 0);
}

// ---------------- prep kernels ----------------

__global__ __launch_bounds__(256) void gather_emb_k(
    const int* __restrict__ x, const float* __restrict__ emb,
    u16* __restrict__ A) {
  int bt = blockIdx.x;
  int tok = x[bt];
  const float* src = emb + (size_t)tok * EDIM;
  u16* dst = A + (size_t)bt * EDIM;
  for (int i = threadIdx.x; i < EDIM; i += 256) dst[i] = f2b(src[i]);
}

// in: fp32 [K][N] row-major  ->  out: bf16 [N][K] row-major
__global__ __launch_bounds__(256) void transpose_cvt_k(
    const float* __restrict__ in, u16* __restrict__ out, int K, int N) {
  __shared__ u16 tile[64][72];
  int n0 = blockIdx.x * 64, k0 = blockIdx.y * 64;
  int tid = threadIdx.x;
  int cr = tid >> 6;   // 0..3
  int cc = tid & 63;
#pragma unroll
  for (int rr = 0; rr < 16; ++rr) {
    int r = rr * 4 + cr;  // k index within tile
    tile[cc][r] = f2b(in[(size_t)(k0 + r) * N + n0 + cc]);
  }
  __syncthreads();
#pragma unroll
  for (int rr = 0; rr < 16; ++rr) {
    int r = rr * 4 + cr;  // n index within tile
    out[(size_t)(n0 + r) * K + k0 + cc] = tile[r][cc];
  }
}

__global__ __launch_bounds__(256) void init_state_k(
    const float* __restrict__ h0, const float* __restrict__ c0,
    u16* __restrict__ h0b, float* __restrict__ c_ws,
    float* __restrict__ h_ws) {
  int i = blockIdx.x * 256 + threadIdx.x;  // 32768 total
  h0b[i] = f2b(h0[i]);
  c_ws[i] = c0[i];
  h_ws[i] = h0[i];
}

__global__ __launch_bounds__(256) void copy_hc_k(
    const float* __restrict__ h_ws, const float* __restrict__ c_ws,
    float* __restrict__ out) {
  int i = blockIdx.x * 256 + threadIdx.x;  // 32768 total
  out[i] = h_ws[i];
  out[BATCH * HDIM + i] = c_ws[i];
}

// ---------------- bf16 MFMA GEMM: C[M][N] = A[M][K] * BT[N][K]^T + bias ----
// 128x128 tile, BK=64, 256 threads (4 waves in 2x2 quadrants), m97 structure.

__global__ __launch_bounds__(256) void gemm_bf16_k(
    const u16* __restrict__ A,    // [M][K] bf16
    const u16* __restrict__ BT,   // [N][K] bf16 (B transposed)
    const float* __restrict__ bias,  // [N] or nullptr
    float* __restrict__ C,        // [M][N] fp32
    int M, int N, int K) {
  __shared__ u16 As[128 * 64];
  __shared__ u16 Bs[128 * 64];
  const int tid = threadIdx.x;
  const int w = tid >> 6, lane = tid & 63;
  const int lo16 = lane & 15, hi4 = lane >> 4;
  const int m0 = blockIdx.y * 128, n0 = blockIdx.x * 128;
  const int wr = w >> 1, wc = w & 1;  // 64x64 quadrant per wave
  f32x4 acc[4][4] = {};

  const int srow = lane >> 3;        // 0..7 (row within 8-row chunk)
  const int scol = (lane & 7) * 8;   // element col offset (8 bf16 = 16B)

  for (int k0 = 0; k0 < K; k0 += 64) {
    __syncthreads();  // protect LDS from previous iteration's readers
#pragma unroll
    for (int r = 0; r < 4; ++r) {
      int blkrow = (r * 4 + w) * 8 + srow;  // 0..127
      gload16(A + (size_t)(m0 + blkrow) * K + k0 + scol,
              As + (r * 4 + w) * 512);
      gload16(BT + (size_t)(n0 + blkrow) * K + k0 + scol,
              Bs + (r * 4 + w) * 512);
    }
    __syncthreads();  // drains vmcnt (compiler emits waitcnt before barrier)

    bf16x8 af[4][2], bfr[4][2];
#pragma unroll
    for (int mi = 0; mi < 4; ++mi)
#pragma unroll
      for (int kk = 0; kk < 2; ++kk)
        af[mi][kk] = *reinterpret_cast<const bf16x8*>(
            As + (wr * 64 + mi * 16 + lo16) * 64 + kk * 32 + hi4 * 8);
#pragma unroll
    for (int nj = 0; nj < 4; ++nj)
#pragma unroll
      for (int kk = 0; kk < 2; ++kk)
        bfr[nj][kk] = *reinterpret_cast<const bf16x8*>(
            Bs + (wc * 64 + nj * 16 + lo16) * 64 + kk * 32 + hi4 * 8);
#pragma unroll
    for (int mi = 0; mi < 4; ++mi)
#pragma unroll
      for (int nj = 0; nj < 4; ++nj)
#pragma unroll
        for (int kk = 0; kk < 2; ++kk)
          acc[mi][nj] = mfma16(af[mi][kk], bfr[nj][kk], acc[mi][nj]);
  }

  const int row0 = m0 + wr * 64, col0 = n0 + wc * 64;
#pragma unroll
  for (int mi = 0; mi < 4; ++mi) {
#pragma unroll
    for (int nj = 0; nj < 4; ++nj) {
      int col = col0 + nj * 16 + lo16;
      float bv = bias ? bias[col] : 0.f;
#pragma unroll
      for (int j = 0; j < 4; ++j) {
        int row = row0 + mi * 16 + hi4 * 4 + j;
        C[(size_t)row * N + col] = acc[mi][nj][j] + bv;
      }
    }
  }
}

// ---------------- LSTM step ----------------
// grid 64 blocks x 256 threads. Block nb owns h-cols [nb*16, nb*16+16).
// Wave w computes gate w's z panel (32 rows x 16 cols), K=1024 via MFMA.
// z = xW[:,t,:] (acc init) + h @ U. Gates fused via LDS z exchange.

__global__ __launch_bounds__(256) void lstm_step_k(
    const float* __restrict__ xW,      // [2048][4096] (bias already added)
    const u16* __restrict__ h_src,     // bf16, row b at h_src + b*h_stride
    int h_stride,
    const u16* __restrict__ UT,        // [4096][1024] bf16 (U transposed)
    float* __restrict__ c_ws,          // [32][1024] fp32 state (in/out)
    float* __restrict__ h_ws,          // [32][1024] fp32 h (out)
    u16* __restrict__ seq,             // [2048][1024] bf16, write row b*64+t
    int t) {
  __shared__ u16 Hs[32 * 64];   // h tile   [32][64]
  __shared__ u16 Us[64 * 64];   // U tile   [64 zcols][64]
  __shared__ float Zs[32 * 64]; // z block  [32][4 gates *16]
  const int tid = threadIdx.x;
  const int w = tid >> 6, lane = tid & 63;
  const int lo16 = lane & 15, hi4 = lane >> 4;
  const int nb = blockIdx.x;
  const int colg = w * HDIM + nb * 16 + lo16;  // this wave's z column

  f32x4 acc[2];
#pragma unroll
  for (int mi = 0; mi < 2; ++mi)
#pragma unroll
    for (int j = 0; j < 4; ++j) {
      int b = mi * 16 + hi4 * 4 + j;
      acc[mi][j] = xW[(size_t)(b * T_STEPS + t) * GDIM + colg];
    }

  const int srow = lane >> 3, scol = (lane & 7) * 8;
  for (int k0 = 0; k0 < HDIM; k0 += 64) {
    __syncthreads();
    // H tile: rows 0..31 (4 waves x 8 rows)
    gload16(h_src + (size_t)(w * 8 + srow) * h_stride + k0 + scol,
            Hs + w * 512);
    // U tile: zrow 0..63 -> gate = zrow>>4, col-in-16 = zrow&15
#pragma unroll
    for (int r = 0; r < 2; ++r) {
      int zr = (r * 4 + w) * 8 + srow;
      int grow = (zr >> 4) * HDIM + nb * 16 + (zr & 15);
      gload16(UT + (size_t)grow * HDIM + k0 + scol,
              Us + (r * 4 + w) * 512);
    }
    __syncthreads();
#pragma unroll
    for (int kk = 0; kk < 2; ++kk) {
      bf16x8 bfr = *reinterpret_cast<const bf16x8*>(
          Us + (w * 16 + lo16) * 64 + kk * 32 + hi4 * 8);
#pragma unroll
      for (int mi = 0; mi < 2; ++mi) {
        bf16x8 af = *reinterpret_cast<const bf16x8*>(
            Hs + (mi * 16 + lo16) * 64 + kk * 32 + hi4 * 8);
        acc[mi] = mfma16(af, bfr, acc[mi]);
      }
    }
  }

  __syncthreads();
#pragma unroll
  for (int mi = 0; mi < 2; ++mi)
#pragma unroll
    for (int j = 0; j < 4; ++j)
      Zs[(mi * 16 + hi4 * 4 + j) * 64 + w * 16 + lo16] = acc[mi][j];
  __syncthreads();

#pragma unroll
  for (int r = 0; r < 2; ++r) {
    int e = r * 256 + tid;       // 512 elems = 32 b x 16 hc
    int b = e >> 4, hc = e & 15;
    float zi = Zs[b * 64 + hc];
    float zf = Zs[b * 64 + 16 + hc];
    float zg = Zs[b * 64 + 32 + hc];
    float zo = Zs[b * 64 + 48 + hc];
    int col = nb * 16 + hc;
    size_t cidx = (size_t)b * HDIM + col;
    float c_old = c_ws[cidx];
    float ig = 1.f / (1.f + __expf(-zi));
    float fg = 1.f / (1.f + __expf(-zf));
    float gg = tanhf(zg);
    float og = 1.f / (1.f + __expf(-zo));
    float cn = fg * c_old + ig * gg;
    float hn = og * tanhf(cn);
    c_ws[cidx] = cn;
    h_ws[cidx] = hn;
    seq[(size_t)(b * T_STEPS + t) * HDIM + col] = f2b(hn);
  }
}

// ---------------- launcher ----------------

extern "C" void kernel_launch(void* const* d_in, const int* in_sizes, int n_in,
                              void* d_out, int out_size, void* d_ws,
                              size_t ws_size, hipStream_t stream) {
  const int* x = (const int*)d_in[0];
  const float* state_h = (const float*)d_in[1];
  const float* state_c = (const float*)d_in[2];
  const float* emb = (const float*)d_in[3];
  const float* W = (const float*)d_in[4];
  const float* U = (const float*)d_in[5];
  const float* bvec = (const float*)d_in[6];
  const float* dW = (const float*)d_in[7];
  const float* db = (const float*)d_in[8];
  float* out = (float*)d_out;
  char* ws = (char*)d_ws;

  size_t off = 0;
  auto alloc = [&](size_t bytes) {
    void* p = ws + off;
    off += (bytes + 255) & ~(size_t)255;
    return p;
  };
  u16* A_emb = (u16*)alloc(2048ull * EDIM * 2);      //  2.0 MB  emb bf16 [2048][512]
  u16* WbT   = (u16*)alloc((size_t)GDIM * EDIM * 2); //  4.0 MB  [4096][512]
  u16* UbT   = (u16*)alloc((size_t)GDIM * HDIM * 2); //  8.4 MB  [4096][1024]
  u16* DbT   = (u16*)alloc((size_t)VDIM * HDIM * 2); // 65.5 MB  [32000][1024]
  float* xW  = (float*)alloc(2048ull * GDIM * 4);    // 33.6 MB  [2048][4096]
  u16* seq   = (u16*)alloc(2048ull * HDIM * 2);      //  4.2 MB  [2048][1024]
  u16* h0b   = (u16*)alloc((size_t)BATCH * HDIM * 2);
  float* h_ws = (float*)alloc((size_t)BATCH * HDIM * 4);
  float* c_ws = (float*)alloc((size_t)BATCH * HDIM * 4);
  if (off > ws_size) return;  // workspace insufficient (~118.4 MB needed)

  gather_emb_k<<<2048, 256, 0, stream>>>(x, emb, A_emb);
  transpose_cvt_k<<<dim3(GDIM / 64, EDIM / 64), 256, 0, stream>>>(W, WbT, EDIM, GDIM);
  transpose_cvt_k<<<dim3(GDIM / 64, HDIM / 64), 256, 0, stream>>>(U, UbT, HDIM, GDIM);
  transpose_cvt_k<<<dim3(VDIM / 64, HDIM / 64), 256, 0, stream>>>(dW, DbT, HDIM, VDIM);
  init_state_k<<<128, 256, 0, stream>>>(state_h, state_c, h0b, c_ws, h_ws);

  // xW = emb @ W + b : [2048][4096]
  gemm_bf16_k<<<dim3(GDIM / 128, 2048 / 128), 256, 0, stream>>>(
      A_emb, WbT, bvec, xW, 2048, GDIM, EDIM);

  for (int t = 0; t < T_STEPS; ++t) {
    const u16* h_src = (t == 0) ? h0b : (seq + (size_t)(t - 1) * HDIM);
    int h_stride = (t == 0) ? HDIM : T_STEPS * HDIM;
    lstm_step_k<<<64, 256, 0, stream>>>(xW, h_src, h_stride, UbT, c_ws, h_ws,
                                        seq, t);
  }

  // logits = seq @ dense_W + dense_b : [2048][32000]
  gemm_bf16_k<<<dim3(VDIM / 128, 2048 / 128), 256, 0, stream>>>(
      seq, DbT, db, out, 2048, VDIM, HDIM);

  copy_hc_k<<<128, 256, 0, stream>>>(h_ws, c_ws, out + 65536000ull);
}